// Round 7
// baseline (168.212 us; speedup 1.0000x reference)
//
#include <hip/hip_runtime.h>
#include <math.h>

// Problem constants (shapes fixed by setup_inputs)
#define B     4
#define DIM   256
#define NP    128   // nPnt
#define NS    144   // 12*12 unique token_init rows per batch
#define HID   512   // 4*nPnt
#define NROW  576   // B*NS
#define H_OUT 120
#define W_OUT 160

__device__ __forceinline__ float gelu_exact(float x) {
    return 0.5f * x * (1.0f + erff(x * 0.70710678118654752440f));
}

// ---------------------------------------------------------------------------
// K_mlp: fused Q -> layer1 -> layer2 (-> softmax) for BOTH MLPs.
// One block = one (mlp, 4-row tile). grid = 2*144 = 288 blocks, 256 threads.
// Stage A stages pt[b] through LDS in 4 chunks of 32 points (coalesced
// global float4 reads; +1-padded LDS rows -> conflict-free compute reads).
// No global transpose kernel needed.
// ---------------------------------------------------------------------------
__global__ __launch_bounds__(256, 2) void k_mlp(
    const float* __restrict__ ti, const float* __restrict__ pt,
    const float* __restrict__ nr_w1, const float* __restrict__ nr_b1,
    const float* __restrict__ nr_w2, const float* __restrict__ nr_b2,
    const float* __restrict__ na_w1, const float* __restrict__ na_b1,
    const float* __restrict__ na_w2, const float* __restrict__ na_b2,
    float* __restrict__ nadjT, float* __restrict__ attn)
{
    const int mlp  = blockIdx.x / 144;
    const int tile = blockIdx.x % 144;
    const int g0 = tile * 4;        // 4 consecutive rows, never crosses batch
    const int b  = g0 / NS;
    const int n0 = g0 % NS;
    const int t  = threadIdx.x;

    const float* __restrict__ w1 = mlp ? na_w1 : nr_w1;
    const float* __restrict__ b1 = mlp ? na_b1 : nr_b1;
    const float* __restrict__ w2 = mlp ? na_w2 : nr_w2;
    const float* __restrict__ b2 = mlp ? na_b2 : nr_b2;

    __shared__ float xs[4][DIM];        //  4 KB   ti rows
    __shared__ float parA[2][4][NP];    //  4 KB   Q partials (2 d-halves)
    __shared__ float qs[4][NP];         //  2 KB
    union BU {                          // Stage-A pts overlaps Stage-B/C bufs
        float pts[32][DIM + 1];         // 32.9 KB  pt chunk (padded rows)
        struct {
            float hs[4][HID];           //  8 KB
            float par[8][4][NP];        // 16 KB
            float red[4][NP];           //  2 KB
        } bc;
    };
    __shared__ BU u;                    // total ~43 KB -> 2 blocks/CU

    // ---- Stage A: Q[4][128] = ti_rows @ pt^T via LDS chunks ---------------
    {
        const int r = t >> 6, c = t & 63;
        ((float4*)xs[r])[c] = ((const float4*)ti)[(size_t)(g0 + r) * 64 + c];
    }

    const int p_l = t & 31;             // point within chunk
    const int rr  = (t >> 5) & 3;       // row
    const int dh  = t >> 7;             // d-half
    for (int chunk = 0; chunk < 4; ++chunk) {
        const int p0 = chunk * 32;
        // stage pt[b, p0..p0+31, :] -> pts (coalesced float4 reads)
        const float4* __restrict__ src =
            (const float4*)pt + (size_t)(b * NP + p0) * 64;
        #pragma unroll
        for (int i = t; i < 32 * 64; i += 256) {
            const int row = i >> 6, c4 = i & 63;
            const float4 v = src[(size_t)row * 64 + c4];
            float* __restrict__ dst = &u.pts[row][c4 * 4];
            dst[0] = v.x; dst[1] = v.y; dst[2] = v.z; dst[3] = v.w;
        }
        __syncthreads();                // pts (and, on chunk 0, xs) ready
        float acc = 0.f;
        #pragma unroll 8
        for (int d2 = 0; d2 < 128; ++d2) {
            const int d = dh * 128 + d2;
            acc += xs[rr][d] * u.pts[p_l][d];
        }
        parA[dh][rr][p0 + p_l] = acc;
        __syncthreads();                // pts consumed; safe to overwrite
    }

    const int p  = t & 127;
    const int rh = t >> 7;              // this thread covers rows rh and rh+2
    qs[rh][p]     = (parA[0][rh][p]     + parA[1][rh][p])     * 0.0625f;
    qs[rh + 2][p] = (parA[0][rh + 2][p] + parA[1][rh + 2][p]) * 0.0625f;
    __syncthreads();

    // ---- Stage B: H = gelu(b1 + Q @ w1) -----------------------------------
    {
        const int kq = t & 127;         // k-quad: k0 = kq*4 covers all 512 k
        const int k0 = kq * 4;
        float4 acc0 = *(const float4*)(b1 + k0);
        float4 acc1 = acc0;
        const float* __restrict__ wp = w1 + k0;
        #pragma unroll 8
        for (int pp = 0; pp < NP; ++pp) {
            const float4 w4 = *(const float4*)(wp + (size_t)pp * HID);
            const float q0 = qs[rh][pp];
            const float q1 = qs[rh + 2][pp];
            acc0.x += q0*w4.x; acc0.y += q0*w4.y;
            acc0.z += q0*w4.z; acc0.w += q0*w4.w;
            acc1.x += q1*w4.x; acc1.y += q1*w4.y;
            acc1.z += q1*w4.z; acc1.w += q1*w4.w;
        }
        float4 o0, o1;
        o0.x = gelu_exact(acc0.x); o0.y = gelu_exact(acc0.y);
        o0.z = gelu_exact(acc0.z); o0.w = gelu_exact(acc0.w);
        o1.x = gelu_exact(acc1.x); o1.y = gelu_exact(acc1.y);
        o1.z = gelu_exact(acc1.z); o1.w = gelu_exact(acc1.w);
        ((float4*)u.bc.hs[rh])[kq]     = o0;
        ((float4*)u.bc.hs[rh + 2])[kq] = o1;
    }
    __syncthreads();

    // ---- Stage C: logits = b2 + H @ w2 (k split over 8 groups) ------------
    {
        const int pq = t & 31;          // p-quad: p0 = pq*4
        const int p0 = pq * 4;
        const int kg = t >> 5;          // k-group 0..7, 64 k each
        float4 a0 = make_float4(0.f,0.f,0.f,0.f);
        float4 a1 = a0, a2 = a0, a3 = a0;
        const float4* __restrict__ w24 = (const float4*)(w2 + p0);
        #pragma unroll 8
        for (int i = 0; i < 64; ++i) {
            const int k = kg * 64 + i;
            const float4 w4 = w24[(size_t)k * 32];
            const float h0 = u.bc.hs[0][k], h1 = u.bc.hs[1][k];
            const float h2 = u.bc.hs[2][k], h3 = u.bc.hs[3][k];
            a0.x += h0*w4.x; a0.y += h0*w4.y; a0.z += h0*w4.z; a0.w += h0*w4.w;
            a1.x += h1*w4.x; a1.y += h1*w4.y; a1.z += h1*w4.z; a1.w += h1*w4.w;
            a2.x += h2*w4.x; a2.y += h2*w4.y; a2.z += h2*w4.z; a2.w += h2*w4.w;
            a3.x += h3*w4.x; a3.y += h3*w4.y; a3.z += h3*w4.z; a3.w += h3*w4.w;
        }
        ((float4*)u.bc.par[kg][0])[pq] = a0;
        ((float4*)u.bc.par[kg][1])[pq] = a1;
        ((float4*)u.bc.par[kg][2])[pq] = a2;
        ((float4*)u.bc.par[kg][3])[pq] = a3;
    }
    __syncthreads();

    // ---- Reduce + emit ----------------------------------------------------
    float lg0 = b2[p], lg1 = lg0;
    #pragma unroll
    for (int kg = 0; kg < 8; ++kg) {
        lg0 += u.bc.par[kg][rh][p];
        lg1 += u.bc.par[kg][rh + 2][p];
    }

    if (mlp == 0) {
        float* __restrict__ dst = nadjT + (size_t)(b * NP + p) * NS + n0;
        dst[rh]     = lg0;
        dst[rh + 2] = lg1;
    } else {
        u.bc.red[rh][p] = lg0; u.bc.red[rh + 2][p] = lg1;
        __syncthreads();
        for (int s = 64; s > 0; s >>= 1) {
            if (p < s) {
                u.bc.red[rh][p] =
                    fmaxf(u.bc.red[rh][p], u.bc.red[rh][p + s]);
                u.bc.red[rh + 2][p] =
                    fmaxf(u.bc.red[rh + 2][p], u.bc.red[rh + 2][p + s]);
            }
            __syncthreads();
        }
        const float m0 = u.bc.red[rh][0], m1 = u.bc.red[rh + 2][0];
        __syncthreads();
        const float e0 = expf(lg0 - m0), e1 = expf(lg1 - m1);
        u.bc.red[rh][p] = e0; u.bc.red[rh + 2][p] = e1;
        __syncthreads();
        for (int s = 64; s > 0; s >>= 1) {
            if (p < s) {
                u.bc.red[rh][p]     += u.bc.red[rh][p + s];
                u.bc.red[rh + 2][p] += u.bc.red[rh + 2][p + s];
            }
            __syncthreads();
        }
        attn[(size_t)(g0 + rh) * NP + p]     = e0 / u.bc.red[rh][0];
        attn[(size_t)(g0 + rh + 2) * NP + p] = e1 / u.bc.red[rh + 2][0];
    }
}

// ---------------------------------------------------------------------------
// K_fold: fused (node_w/node_h einsums + tf MLP).  For (b,p), thread d:
//   v[m] = sum over the 12x12 grid (regs, fully unrolled; coalesced ti reads)
//   tf[b,p,d] = b2 + sum_k gelu(b1[k] + sum_m v[m]*w1p[m][k]) * w2[k]
// grid = 4*128 = 512 blocks.
// ---------------------------------------------------------------------------
__global__ __launch_bounds__(256) void k_fold(
    const float* __restrict__ nadjT, const float* __restrict__ ti,
    const float* __restrict__ w1, const float* __restrict__ b1,
    const float* __restrict__ w2, const float* __restrict__ b2,
    float* __restrict__ tf)
{
    const int b = blockIdx.x >> 7;
    const int p = blockIdx.x & 127;
    const int t = threadIdx.x;
    __shared__ float an[NS];
    __shared__ float w1p[24][48];
    __shared__ float b1s[48];
    __shared__ float w2s[48];

    if (t < 36) {   // 144 floats = 36 float4, coalesced from nadjT row
        ((float4*)an)[t] =
            ((const float4*)(nadjT + (size_t)(b * NP + p) * NS))[t];
    }
    if (t >= 192 && t < 240) {
        const int k = t - 192;
        b1s[k] = b1[k];
        w2s[k] = w2[k];
    }
    for (int i = t; i < 24 * 48; i += 256) {
        const int m = i / 48, k = i - m * 48;
        w1p[m][k] = w1[(2 * m) * 48 + k] + w1[(2 * m + 1) * 48 + k];
    }
    __syncthreads();

    const int d = t;
    const float* __restrict__ tb = ti + (size_t)b * NS * DIM + d;
    float v[24];
    #pragma unroll
    for (int m = 0; m < 24; ++m) v[m] = 0.f;
    #pragma unroll
    for (int y = 0; y < 12; ++y) {
        #pragma unroll
        for (int x = 0; x < 12; ++x) {
            const int n = y * 12 + x;
            const float tv = tb[n * DIM];
            const float a  = an[n];
            v[y]      += a * tv;   // node_w: m=y, j=x
            v[12 + x] += a * tv;   // node_h: m=12+x, j=y
        }
    }
    const float c = 0.40824829046386301637f;  // 2/sqrt(24)
    #pragma unroll
    for (int m = 0; m < 24; ++m) v[m] *= c;

    float acc = b2[0];
    for (int k = 0; k < 48; ++k) {
        float tt = b1s[k];
        #pragma unroll
        for (int m = 0; m < 24; ++m) tt += v[m] * w1p[m][k];
        acc += gelu_exact(tt) * w2s[k];
    }
    tf[(size_t)(b * NP + p) * DIM + d] = acc;
}

// ---------------------------------------------------------------------------
// K_final: row[d] = ti[g][d] + sum_p attn[g][p]*tf[b,p,d], then broadcast-
// scatter the row to out[b,h,w,:] for its (h,w) set. 2 blocks per row g
// (each takes 5 of the 10 h-lines) for write parallelism. grid = 1152.
// ---------------------------------------------------------------------------
__global__ __launch_bounds__(256) void k_final(
    const float* __restrict__ attn, const float* __restrict__ tf,
    const float* __restrict__ ti, float4* __restrict__ out)
{
    const int g    = blockIdx.x >> 1;
    const int half = blockIdx.x & 1;
    const int b = g / NS;
    const int n = g % NS;
    const int t = threadIdx.x;
    const int dq = t & 63;
    const int pg = t >> 6;

    __shared__ float  at[NP];
    __shared__ float4 par4[4][64];
    __shared__ float4 rowf[64];

    if (t < NP) at[t] = attn[(size_t)g * NP + t];
    __syncthreads();

    const float4* __restrict__ tp = (const float4*)tf + (size_t)b * NP * 64 + dq;
    float4 acc = make_float4(0.f, 0.f, 0.f, 0.f);
    #pragma unroll 8
    for (int i = 0; i < 32; ++i) {
        const int pp = pg * 32 + i;
        const float  a  = at[pp];
        const float4 tv = tp[(size_t)pp * 64];
        acc.x += a * tv.x; acc.y += a * tv.y;
        acc.z += a * tv.z; acc.w += a * tv.w;
    }
    par4[pg][dq] = acc;
    __syncthreads();

    if (t < 64) {
        float4 s = par4[0][t];
        const float4 s1 = par4[1][t], s2 = par4[2][t], s3 = par4[3][t];
        const float4 tiv = ((const float4*)ti)[(size_t)g * 64 + t];
        s.x += s1.x + s2.x + s3.x + tiv.x;
        s.y += s1.y + s2.y + s3.y + tiv.y;
        s.z += s1.z + s2.z + s3.z + tiv.z;
        s.w += s1.w + s2.w + s3.w + tiv.w;
        rowf[t] = s;
    }
    __syncthreads();

    // scatter: src(h,w) = (h/10)*12 + (3w)/40 == n  <=>  h in [10y,10y+10),
    // w in [ceil(40x/3), ceil(40x/3 + 40/3)) where n = y*12+x.
    const int y = n / 12, x = n % 12;
    const int w_lo = (40 * x + 2) / 3;
    const int w_hi = (40 * x + 42) / 3;
    const float4 val = rowf[dq];
    const int h0 = 10 * y + 5 * half;
    for (int h = h0; h < h0 + 5; ++h) {
        float4* __restrict__ orow = out + (size_t)((b * H_OUT + h) * W_OUT) * 64 + dq;
        for (int w = w_lo + pg; w < w_hi; w += 4) {
            orow[(size_t)w * 64] = val;
        }
    }
}

extern "C" void kernel_launch(void* const* d_in, const int* in_sizes, int n_in,
                              void* d_out, int out_size, void* d_ws, size_t ws_size,
                              hipStream_t stream) {
    (void)in_sizes; (void)n_in; (void)out_size; (void)ws_size;
    const float* token_init  = (const float*)d_in[0];  // [4,144,256]
    const float* point_token = (const float*)d_in[1];  // [4,128,256]
    const float* nr_w1 = (const float*)d_in[2];
    const float* nr_b1 = (const float*)d_in[3];
    const float* nr_w2 = (const float*)d_in[4];
    const float* nr_b2 = (const float*)d_in[5];
    const float* na_w1 = (const float*)d_in[6];
    const float* na_b1 = (const float*)d_in[7];
    const float* na_w2 = (const float*)d_in[8];
    const float* na_b2 = (const float*)d_in[9];
    const float* tf_w1 = (const float*)d_in[10];
    const float* tf_b1 = (const float*)d_in[11];
    const float* tf_w2 = (const float*)d_in[12];
    const float* tf_b2 = (const float*)d_in[13];

    float* out = (float*)d_out;
    float* ws  = (float*)d_ws;
    float* nadjT = ws;                  //  73,728 f  [b*NP+p][n]
    float* attn  = nadjT + NROW * NP;   //  73,728 f
    float* tf    = attn + NROW * NP;    // 131,072 f   (~1.1 MB total)

    k_mlp<<<288, 256, 0, stream>>>(token_init, point_token,
                                   nr_w1, nr_b1, nr_w2, nr_b2,
                                   na_w1, na_b1, na_w2, na_b2,
                                   nadjT, attn);
    k_fold<<<B * NP, 256, 0, stream>>>(nadjT, token_init,
                                       tf_w1, tf_b1, tf_w2, tf_b2, tf);
    k_final<<<NROW * 2, 256, 0, stream>>>(attn, tf, token_init, (float4*)out);
}